// Round 5
// baseline (178.132 us; speedup 1.0000x reference)
//
#include <hip/hip_runtime.h>

// Problem constants (from reference)
#define N_NODES 12500
#define N_EDGES 200000
#define DIM 32          // IN == OUT == ATTN == 32
#define N_REL 200
#define N_BASES 50

// Padded edge capacity: per-rel lists padded to multiples of 16.
// Dummy slots are EXACTLY PE_MAX - N_EDGES = 3008 (per-rel pads + tail).
#define PE_MAX 203008
#define N_DUMMY_BLOCKS 8

// Counting-sort blocking (R2/R3 structure: LDS histograms, transposed tables,
// Hillis-Steele scan; no global atomics in the sort).
#define NB_BLK 200
#define CHUNK 1000            // NB_BLK * CHUNK == N_EDGES exactly

#define DEGZ_BLOCKS 13        // 13*1024 >= 12500
#define NODEOUT_BLOCKS 98     // ceil(12500/128)
#define GATE_BLOCKS 782       // 782*256 >= 200000 (R5: 64 edges/wave)
#define EDGE_BLOCKS 793       // 793*256 == PE_MAX exactly

// ws layout (bytes):
//   [0, 409600)         bf16 relwT_bf[200][32][32]  TRANSPOSED: [r][o][i]
//   [409600, +8192)     bf16 aw_bf[32][128]         (= A_w, row-major)
//   [417792, +160000)   int  blockCountsT[N_REL][NB_BLK]
//   [577792, +160000)   int  blockBaseT[N_REL][NB_BLK]
//   [737792, +816)      int  offs[201]   (offs[200] = padded total)
//   [738608, +800)      int  tots[200]
//   [739408, +800000)   f32  a_gate[N_EDGES]
//   [1539408, +50000)   int  deg[N_NODES]
//   [1589408, +16*PE_MAX) int4 slot4[PE_MAX] {src, tgt(-1=dummy), a_bits, rel}
#define AWBF_OFF  (N_REL * 1024 * 2)
#define BCT_OFF   (AWBF_OFF + 32 * 128 * 2)
#define BBT_OFF   (BCT_OFF + N_REL * NB_BLK * 4)
#define OFFS_OFF  (BBT_OFF + N_REL * NB_BLK * 4)
#define TOTS_OFF  (OFFS_OFF + 816)
#define AGATE_OFF (TOTS_OFF + 800)
#define DEG_OFF   (AGATE_OFF + N_EDGES * 4)
#define SLOT_OFF  (DEG_OFF + 50000)              // 1589408, 16B-aligned

typedef __attribute__((ext_vector_type(8))) short short8;   // 8 bf16 (4 VGPRs)
typedef __attribute__((ext_vector_type(4))) float f32x4;    // MFMA acc

__device__ __forceinline__ unsigned short f2bf(float x) {
    union { float f; unsigned u; } v; v.f = x;
    unsigned r = (v.u + 0x7FFFu + ((v.u >> 16) & 1u)) >> 16;
    return (unsigned short)r;
}

__device__ __forceinline__ short8 cvt8(float4 a, float4 b) {
    short8 r;
    r[0] = (short)f2bf(a.x); r[1] = (short)f2bf(a.y);
    r[2] = (short)f2bf(a.z); r[3] = (short)f2bf(a.w);
    r[4] = (short)f2bf(b.x); r[5] = (short)f2bf(b.y);
    r[6] = (short)f2bf(b.z); r[7] = (short)f2bf(b.w);
    return r;
}

#define MFMA(A, B, C) __builtin_amdgcn_mfma_f32_16x16x32_bf16(A, B, C, 0, 0, 0)

// Launch 1 — prep: [0,200) rel_w basis combine; 200 converts Aw; [201,214)
// zero deg; [214,414) per-block LDS rel-histogram -> blockCountsT.
__global__ __launch_bounds__(256) void prep_kernel(
    const float* __restrict__ weight,   // [50,32,32]
    const float* __restrict__ w_comp,   // [200,50]
    const float* __restrict__ Aw,       // [32,128]
    const int*  __restrict__ rel,       // [E]
    unsigned short* __restrict__ relwT_bf,
    unsigned short* __restrict__ aw_bf,
    int* __restrict__ deg,
    int* __restrict__ blockCountsT)
{
    int b = blockIdx.x, tid = threadIdx.x;
    if (b < N_REL) {
        __shared__ float wc[N_BASES];
        if (tid < N_BASES) wc[tid] = w_comp[b * N_BASES + tid];
        __syncthreads();
        const float* wp = weight + tid * 4;
        float4 acc = make_float4(0.f, 0.f, 0.f, 0.f);
        #pragma unroll 10
        for (int bb = 0; bb < N_BASES; bb++) {
            float4 w = *(const float4*)(wp + bb * 1024);
            float c = wc[bb];
            acc.x = fmaf(c, w.x, acc.x); acc.y = fmaf(c, w.y, acc.y);
            acc.z = fmaf(c, w.z, acc.z); acc.w = fmaf(c, w.w, acc.w);
        }
        // flat f = tid*4 + j over [i][o] (o fastest); write transposed [r][o][i]
        int i  = tid >> 3;
        int o0 = (tid * 4) & 31;
        unsigned short* dst = relwT_bf + b * 1024 + i;
        dst[(o0 + 0) * 32] = f2bf(acc.x);
        dst[(o0 + 1) * 32] = f2bf(acc.y);
        dst[(o0 + 2) * 32] = f2bf(acc.z);
        dst[(o0 + 3) * 32] = f2bf(acc.w);
    } else if (b == N_REL) {
        for (int x = tid; x < 32 * 128; x += 256) aw_bf[x] = f2bf(Aw[x]);
    } else if (b < N_REL + 1 + DEGZ_BLOCKS) {
        int base = (b - (N_REL + 1)) * 1024 + tid * 4;
        if (base < N_NODES)   // N_NODES % 4 == 0, so full int4 is in-bounds
            *(int4*)(deg + base) = make_int4(0, 0, 0, 0);
    } else {
        __shared__ int h[N_REL];
        int blk = b - (N_REL + 1 + DEGZ_BLOCKS);
        for (int x = tid; x < N_REL; x += 256) h[x] = 0;
        __syncthreads();
        int e0 = blk * CHUNK;
        for (int e = e0 + tid; e < e0 + CHUNK; e += 256) {
            int r = rel[e]; r = r < 0 ? 0 : (r >= N_REL ? N_REL - 1 : r);
            atomicAdd(&h[r], 1);
        }
        __syncthreads();
        for (int x = tid; x < N_REL; x += 256)
            blockCountsT[x * NB_BLK + blk] = h[x];
    }
}

// Launch 2 — gate (blocks [0,782)) + scan (block 782).
// R5: one wave = 64 edges (4 MFMA groups). Lane owns one edge's indices
// (coalesced); ALL 4 groups' feature loads are issued before any MFMA
// (4 independent chains = the MLP that R4's 16-edge waves lacked); bA
// fragments loaded ONCE per wave and reused across groups.
__global__ __launch_bounds__(256) void gate_scan_kernel(
    const float* __restrict__ node_feat,  // [N,32]
    const float* __restrict__ ttr,        // [E,32]
    const float* __restrict__ tre,        // [E,32]
    const float* __restrict__ Ab,         // [32]
    const float* __restrict__ Bw,         // [1,32]
    const float* __restrict__ Bb,         // [1]
    const int*  __restrict__ edge0,       // [E]
    const int*  __restrict__ edge1,       // [E]
    const unsigned short* __restrict__ aw_bf,   // [32][128] bf16
    const int* __restrict__ blockCountsT,
    int* __restrict__ blockBaseT,
    int* __restrict__ offs, int* __restrict__ tots,
    float* __restrict__ a_gate,
    int* __restrict__ deg)
{
    int b = blockIdx.x, tid = threadIdx.x;
    if (b == GATE_BLOCKS) {
        // ---- scan role (R3 structure: int4 reduce + Hillis-Steele) ----
        __shared__ int s0[256];
        __shared__ int pval[256];
        int tot = 0;
        if (tid < N_REL) {
            const int4* cp = (const int4*)(blockCountsT + tid * NB_BLK);
            #pragma unroll 5
            for (int bb = 0; bb < NB_BLK / 4; bb++) {
                int4 c = cp[bb];
                tot += c.x + c.y + c.z + c.w;
            }
        }
        int p = (tid < N_REL) ? ((tot + 15) & ~15) : 0;
        pval[tid] = p;
        s0[tid] = p;
        __syncthreads();
        #pragma unroll
        for (int d = 1; d < 256; d <<= 1) {
            int v = s0[tid];
            if (tid >= d) v += s0[tid - d];
            __syncthreads();
            s0[tid] = v;
            __syncthreads();
        }
        int off = s0[tid] - pval[tid];
        if (tid < N_REL) { offs[tid] = off; tots[tid] = tot; }
        if (tid == 255) offs[N_REL] = s0[255];
        if (tid < N_REL) {
            const int4* cp = (const int4*)(blockCountsT + tid * NB_BLK);
            int4* bp = (int4*)(blockBaseT + tid * NB_BLK);
            int run = off;
            #pragma unroll 5
            for (int bb = 0; bb < NB_BLK / 4; bb++) {
                int4 c = cp[bb];
                int4 w;
                w.x = run;
                w.y = w.x + c.x;
                w.z = w.y + c.y;
                w.w = w.z + c.z;
                run = w.w + c.w;
                bp[bb] = w;
            }
        }
        return;
    }
    // ---- gate role: one wave = 64 consecutive edges, 4 groups of 16 ----
    int wave = tid >> 6;
    int lane = tid & 63;
    int m = lane & 15;          // edge row within group / out col
    int q = lane >> 4;          // k-chunk / row-group
    int wbase = b * 256 + wave * 64;

    int e_lane = wbase + lane;
    bool ein = e_lane < N_EDGES;
    int e_cl = ein ? e_lane : N_EDGES - 1;
    int s_ld = edge0[e_cl]; s_ld = s_ld < 0 ? 0 : (s_ld >= N_NODES ? N_NODES - 1 : s_ld);
    int t_ld = edge1[e_cl]; t_ld = t_ld < 0 ? 0 : (t_ld >= N_NODES ? N_NODES - 1 : t_ld);
    if (ein) atomicAdd(&deg[t_ld], 1);

    // bA fragments: depend on (m,q) only -> load once, reuse for all 4 groups
    short8 bA[4][2];
    #pragma unroll
    for (int hh = 0; hh < 2; hh++)
        #pragma unroll
        for (int c = 0; c < 4; c++)
            bA[c][hh] = *(const short8*)(aw_bf + (16 * hh + m) * 128 + 32 * c + 8 * q);

    // issue ALL feature loads (4 independent groups), convert per group
    short8 fsrc[4], ftgt[4], fre_[4], ftr_[4];
    #pragma unroll
    for (int g = 0; g < 4; g++) {
        int s_m = __shfl(s_ld, g * 16 + m, 64);
        int t_m = __shfl(t_ld, g * 16 + m, 64);
        int e_m = wbase + g * 16 + m; if (e_m >= N_EDGES) e_m = N_EDGES - 1;
        const float* sp = node_feat + s_m * DIM + q * 8;
        float4 sv0 = *(const float4*)sp, sv1 = *(const float4*)(sp + 4);
        const float* tp = node_feat + t_m * DIM + q * 8;
        float4 tv0 = *(const float4*)tp, tv1 = *(const float4*)(tp + 4);
        const float* rp = tre + e_m * DIM + q * 8;      // coalesced stream
        float4 rv0 = *(const float4*)rp, rv1 = *(const float4*)(rp + 4);
        const float* qp = ttr + e_m * DIM + q * 8;      // coalesced stream
        float4 qv0 = *(const float4*)qp, qv1 = *(const float4*)(qp + 4);
        fsrc[g] = cvt8(sv0, sv1);
        ftgt[g] = cvt8(tv0, tv1);
        fre_[g] = cvt8(rv0, rv1);
        ftr_[g] = cvt8(qv0, qv1);
    }

    float ab0 = Ab[m], ab1 = Ab[16 + m];
    float bw0 = Bw[m], bw1 = Bw[16 + m], Bb0 = Bb[0];

    #pragma unroll
    for (int g = 0; g < 4; g++) {
        f32x4 h0 = {ab0, ab0, ab0, ab0};
        f32x4 h1 = {ab1, ab1, ab1, ab1};
        h0 = MFMA(fsrc[g], bA[0][0], h0);  h1 = MFMA(fsrc[g], bA[0][1], h1);
        h0 = MFMA(ftgt[g], bA[1][0], h0);  h1 = MFMA(ftgt[g], bA[1][1], h1);
        h0 = MFMA(fre_[g], bA[2][0], h0);  h1 = MFMA(fre_[g], bA[2][1], h1);
        h0 = MFMA(ftr_[g], bA[3][0], h0);  h1 = MFMA(ftr_[g], bA[3][1], h1);

        float av[4];
        #pragma unroll
        for (int v = 0; v < 4; v++) {
            float p = fmaxf(h0[v], 0.f) * bw0 + fmaxf(h1[v], 0.f) * bw1;
            p += __shfl_xor(p, 1, 16);
            p += __shfl_xor(p, 2, 16);
            p += __shfl_xor(p, 4, 16);
            p += __shfl_xor(p, 8, 16);
            av[v] = 1.f / (1.f + __expf(-(p + Bb0)));
        }
        if (m == 0) {
            int eo = wbase + g * 16 + 4 * q;     // multiple of 4
            if (eo + 3 < N_EDGES)
                *(float4*)(a_gate + eo) = make_float4(av[0], av[1], av[2], av[3]);
            else
                for (int k = 0; k < 4; k++)
                    if (eo + k < N_EDGES) a_gate[eo + k] = av[k];
        }
    }
}

// Launch 3 — scatter (blocks [0,200)) + dummy-writers ([200,208)) +
// nodeout ([208,306)). nodeout: out[n] = deg[n] * (x[n] @ slw).
__global__ __launch_bounds__(256) void scatter_node_kernel(
    const int* __restrict__ edge0, const int* __restrict__ edge1,
    const int* __restrict__ rel,
    const int* __restrict__ blockBaseT,
    const int* __restrict__ offs, const int* __restrict__ tots,
    const float* __restrict__ a_gate,
    const float* __restrict__ node_feat,  // [N,32]
    const float* __restrict__ slw,        // [32,32] fp32
    const int* __restrict__ deg,
    int4* __restrict__ slot4,
    float* __restrict__ out)              // [N,32]
{
    int blk = blockIdx.x, tid = threadIdx.x;
    if (blk < NB_BLK) {
        __shared__ int cur[N_REL];
        for (int x = tid; x < N_REL; x += 256)
            cur[x] = blockBaseT[x * NB_BLK + blk];
        __syncthreads();
        int e0 = blk * CHUNK;
        for (int e = e0 + tid; e < e0 + CHUNK; e += 256) {
            int r = rel[e];   r = r < 0 ? 0 : (r >= N_REL   ? N_REL   - 1 : r);
            int s = edge0[e]; s = s < 0 ? 0 : (s >= N_NODES ? N_NODES - 1 : s);
            int t = edge1[e]; t = t < 0 ? 0 : (t >= N_NODES ? N_NODES - 1 : t);
            int pos = atomicAdd(&cur[r], 1);
            slot4[pos] = make_int4(s, t, __float_as_int(a_gate[e]), r);
        }
    } else if (blk < NB_BLK + N_DUMMY_BLOCKS) {
        int db = blk - NB_BLK;               // 0..7
        const int4 dummy = make_int4(0, -1, 0, 0);
        for (int r = db; r < N_REL; r += N_DUMMY_BLOCKS) {
            int start = offs[r] + tots[r];
            int end   = offs[r] + ((tots[r] + 15) & ~15);
            for (int j = start + tid; j < end; j += 256)
                slot4[j] = dummy;
        }
        int padTotal = offs[N_REL];
        for (int j = padTotal + db * 256 + tid; j < PE_MAX; j += N_DUMMY_BLOCKS * 256)
            slot4[j] = dummy;
    } else {
        // nodeout: 128 node rows per block, LDS-staged slw + x rows
        __shared__ float slws[32 * 32];
        __shared__ float xs[8 * 32];
        for (int x = tid; x < 32 * 32; x += 256) slws[x] = slw[x];
        __syncthreads();
        int n0 = (blk - (NB_BLK + N_DUMMY_BLOCKS)) * 128;
        int rr = tid >> 5, j = tid & 31;
        for (int pass = 0; pass < 16; pass++) {
            int n = n0 + pass * 8 + rr;
            xs[tid] = (n < N_NODES) ? node_feat[n * 32 + j] : 0.f;
            __syncthreads();
            if (n < N_NODES) {
                float acc = 0.f;
                #pragma unroll
                for (int i = 0; i < 32; i++)
                    acc = fmaf(xs[rr * 32 + i], slws[i * 32 + j], acc);
                out[n * 32 + j] = (float)deg[n] * acc;
            }
            __syncthreads();
        }
    }
}

// Launch 4 — edge: one wave = 64 slots (4 groups of 16; each 16-group is
// single-relation by padding). Lane owns one slot (coalesced 1KB int4 load);
// all 4 groups' src gathers + bM fragments issued before the MFMAs.
__global__ __launch_bounds__(256) void edge_kernel(
    const float* __restrict__ node_feat,  // [N,32]
    const int4* __restrict__ slot4,       // [PE_MAX] {s, t(-1=dummy), a_bits, r}
    const unsigned short* __restrict__ relwT_bf, // [200][32][32] bf16 (T)
    float* __restrict__ out)              // [N,32] fp32 (nodeout-initialized)
{
    int tid  = threadIdx.x;
    int wave = tid >> 6;
    int lane = tid & 63;
    int m = lane & 15;          // edge row (A-frag) / out col n (B,C/D frag)
    int q = lane >> 4;          // quad: k-range / row-group
    int wbase = blockIdx.x * 256 + wave * 64;   // 793*256 == PE_MAX exactly

    int4 v = slot4[wbase + lane];               // coalesced
    int s_ld = v.x, t_ld = v.y, a_ld = v.z, r_ld = v.w;

    short8 fsrc[4], bM[4][2];
    #pragma unroll
    for (int g = 0; g < 4; g++) {
        int r_g = __shfl(r_ld, g * 16, 64);     // uniform within the group
        int s_m = __shfl(s_ld, g * 16 + m, 64);
        const float* sp = node_feat + s_m * DIM + q * 8;
        float4 sv0 = *(const float4*)sp, sv1 = *(const float4*)(sp + 4);
        fsrc[g] = cvt8(sv0, sv1);
        bM[g][0] = *(const short8*)(relwT_bf + r_g * 1024 + m * 32 + 8 * q);
        bM[g][1] = *(const short8*)(relwT_bf + r_g * 1024 + (16 + m) * 32 + 8 * q);
    }

    #pragma unroll
    for (int g = 0; g < 4; g++) {
        f32x4 m0 = {0.f, 0.f, 0.f, 0.f};
        f32x4 m1 = {0.f, 0.f, 0.f, 0.f};
        m0 = MFMA(fsrc[g], bM[g][0], m0);
        m1 = MFMA(fsrc[g], bM[g][1], m1);
        #pragma unroll
        for (int vv = 0; vv < 4; vv++) {
            int row = 4 * q + vv;
            int tv = __shfl(t_ld, g * 16 + row, 64);
            float a_row = __int_as_float(__shfl(a_ld, g * 16 + row, 64));
            if (tv >= 0) {
                atomicAdd(&out[tv * DIM + m],      m0[vv] * a_row);
                atomicAdd(&out[tv * DIM + 16 + m], m1[vv] * a_row);
            }
        }
    }
}

extern "C" void kernel_launch(void* const* d_in, const int* in_sizes, int n_in,
                              void* d_out, int out_size, void* d_ws, size_t ws_size,
                              hipStream_t stream) {
    const float* node_feat = (const float*)d_in[0];
    const float* ttr       = (const float*)d_in[1];
    const float* tre       = (const float*)d_in[2];
    const float* weight    = (const float*)d_in[3];
    const float* w_comp    = (const float*)d_in[4];
    const float* slw       = (const float*)d_in[5];
    const float* Aw        = (const float*)d_in[6];
    const float* Ab        = (const float*)d_in[7];
    const float* Bw        = (const float*)d_in[8];
    const float* Bb        = (const float*)d_in[9];
    const int*  total_edge = (const int*)d_in[10];
    const int*  rel        = (const int*)d_in[11];
    const int*  edge0 = total_edge;
    const int*  edge1 = total_edge + N_EDGES;

    char* ws = (char*)d_ws;
    unsigned short* relwT_bf = (unsigned short*)ws;
    unsigned short* aw_bf    = (unsigned short*)(ws + AWBF_OFF);
    int*  blockCountsT = (int*)(ws + BCT_OFF);
    int*  blockBaseT   = (int*)(ws + BBT_OFF);
    int*  offs         = (int*)(ws + OFFS_OFF);
    int*  tots         = (int*)(ws + TOTS_OFF);
    float* a_gate      = (float*)(ws + AGATE_OFF);
    int*  deg          = (int*)(ws + DEG_OFF);
    int4* slot4        = (int4*)(ws + SLOT_OFF);
    float* out = (float*)d_out;

    prep_kernel<<<N_REL + 1 + DEGZ_BLOCKS + NB_BLK, 256, 0, stream>>>(
        weight, w_comp, Aw, rel, relwT_bf, aw_bf, deg, blockCountsT);

    gate_scan_kernel<<<GATE_BLOCKS + 1, 256, 0, stream>>>(
        node_feat, ttr, tre, Ab, Bw, Bb, edge0, edge1, aw_bf,
        blockCountsT, blockBaseT, offs, tots, a_gate, deg);

    scatter_node_kernel<<<NB_BLK + N_DUMMY_BLOCKS + NODEOUT_BLOCKS, 256, 0, stream>>>(
        edge0, edge1, rel, blockBaseT, offs, tots, a_gate,
        node_feat, slw, deg, slot4, out);

    edge_kernel<<<EDGE_BLOCKS, 256, 0, stream>>>(
        node_feat, slot4, relwT_bf, out);
}

// Round 7
// 172.259 us; speedup vs baseline: 1.0341x; 1.0341x over previous
//
#include <hip/hip_runtime.h>

// Problem constants (from reference)
#define N_NODES 12500
#define N_EDGES 200000
#define DIM 32          // IN == OUT == ATTN == 32
#define N_REL 200
#define N_BASES 50

#define OUT_ELEMS   (N_NODES * DIM)
#define ZERO_BLOCKS ((OUT_ELEMS + 1023) / 1024)   // 391

// Padded edge capacity: per-rel lists padded to multiples of 16.
// Dummy slots <= 200*15 + tail; PE_MAX - 200000 = 3008 exactly.
#define PE_MAX 203008
#define N_DUMMY_BLOCKS 8

// Counting-sort blocking. CHUNK is a multiple of 64 so every 64-edge wave
// group in the fused gate+scatter is fully in-bounds (200000 % 64 == 0).
#define NB_BLK 196
#define CHUNK 1024            // 195*1024 + 320 = 200000; both mult. of 64

#define HIST_BASE (N_REL + 1 + ZERO_BLOCKS)   // 592
#define PREP_BLOCKS (HIST_BASE + NB_BLK)      // 788
#define EDGE_BLOCKS (PE_MAX / 256)            // 793

// ws layout (bytes):
//   [0, 409600)        bf16 relwT_bf[200][32][32]  TRANSPOSED: [r][o][i]
//   [409600, +8192)    bf16 aw_bf[32][128]         (= A_w, row-major)
//   [417792, +2048)    bf16 slwT_bf[32][32]        (= slw transposed [j][i])
//   [419840, +156800)  int  blockCountsT[N_REL][NB_BLK]
//   [576640, +156800)  int  blockBaseT[N_REL][NB_BLK]
//   [733440, +816)     int  offs[201]   (offs[200] = padded total)
//   [734256, +800)     int  tots[200]
//   [735056, +16*PE_MAX) int4 slot4[PE_MAX] {src, tgt(-1=dummy), a_bits, rel}
#define AWBF_OFF  (N_REL * 1024 * 2)
#define SLWT_OFF  (AWBF_OFF + 32 * 128 * 2)
#define BCT_OFF   (SLWT_OFF + 32 * 32 * 2)
#define BBT_OFF   (BCT_OFF + N_REL * NB_BLK * 4)
#define OFFS_OFF  (BBT_OFF + N_REL * NB_BLK * 4)
#define TOTS_OFF  (OFFS_OFF + 816)
#define SLOT_OFF  (TOTS_OFF + 800)            // 735056, 16B-aligned

typedef __attribute__((ext_vector_type(8))) short short8;   // 8 bf16 (4 VGPRs)
typedef __attribute__((ext_vector_type(4))) float f32x4;    // MFMA acc

__device__ __forceinline__ unsigned short f2bf(float x) {
    union { float f; unsigned u; } v; v.f = x;
    unsigned r = (v.u + 0x7FFFu + ((v.u >> 16) & 1u)) >> 16;
    return (unsigned short)r;
}

__device__ __forceinline__ short8 cvt8(float4 a, float4 b) {
    short8 r;
    r[0] = (short)f2bf(a.x); r[1] = (short)f2bf(a.y);
    r[2] = (short)f2bf(a.z); r[3] = (short)f2bf(a.w);
    r[4] = (short)f2bf(b.x); r[5] = (short)f2bf(b.y);
    r[6] = (short)f2bf(b.z); r[7] = (short)f2bf(b.w);
    return r;
}

#define MFMA(A, B, C) __builtin_amdgcn_mfma_f32_16x16x32_bf16(A, B, C, 0, 0, 0)

// Launch 1 — prep: [0,200) rel_w basis -> bf16 transposed; 200: Aw + slwT
// convert; [201,592) out zero-fill (self-loop is back in the edge kernel;
// deg/nodeout machinery deleted); [592,788) per-chunk LDS hist -> blockCountsT.
__global__ __launch_bounds__(256) void prep_kernel(
    const float* __restrict__ weight,   // [50,32,32]
    const float* __restrict__ w_comp,   // [200,50]
    const float* __restrict__ Aw,       // [32,128]
    const float* __restrict__ slw,      // [32,32]
    const int*  __restrict__ rel,       // [E]
    unsigned short* __restrict__ relwT_bf,
    unsigned short* __restrict__ aw_bf,
    unsigned short* __restrict__ slwT_bf,
    int* __restrict__ blockCountsT,
    float* __restrict__ out)
{
    int b = blockIdx.x, tid = threadIdx.x;
    if (b < N_REL) {
        __shared__ float wc[N_BASES];
        if (tid < N_BASES) wc[tid] = w_comp[b * N_BASES + tid];
        __syncthreads();
        const float* wp = weight + tid * 4;
        float4 acc = make_float4(0.f, 0.f, 0.f, 0.f);
        #pragma unroll 10
        for (int bb = 0; bb < N_BASES; bb++) {
            float4 w = *(const float4*)(wp + bb * 1024);
            float c = wc[bb];
            acc.x = fmaf(c, w.x, acc.x); acc.y = fmaf(c, w.y, acc.y);
            acc.z = fmaf(c, w.z, acc.z); acc.w = fmaf(c, w.w, acc.w);
        }
        // flat f = tid*4 + j over [i][o] (o fastest); write transposed [r][o][i]
        int i  = tid >> 3;
        int o0 = (tid * 4) & 31;
        unsigned short* dst = relwT_bf + b * 1024 + i;
        dst[(o0 + 0) * 32] = f2bf(acc.x);
        dst[(o0 + 1) * 32] = f2bf(acc.y);
        dst[(o0 + 2) * 32] = f2bf(acc.z);
        dst[(o0 + 3) * 32] = f2bf(acc.w);
    } else if (b == N_REL) {
        for (int x = tid; x < 32 * 128; x += 256) aw_bf[x] = f2bf(Aw[x]);
        for (int x = tid; x < 32 * 32; x += 256) {
            int i = x >> 5, j = x & 31;          // slw[i][j]
            slwT_bf[j * 32 + i] = f2bf(slw[x]);
        }
    } else if (b < HIST_BASE) {
        int base = (b - (N_REL + 1)) * 1024 + tid * 4;
        if (base + 3 < OUT_ELEMS)
            *(float4*)(out + base) = make_float4(0.f, 0.f, 0.f, 0.f);
        else
            for (int k = 0; k < 4; k++)
                if (base + k < OUT_ELEMS) out[base + k] = 0.f;
    } else {
        // per-block histogram: LDS atomics only; transposed stores so the
        // scan's per-bin reduction reads are contiguous int4s.
        __shared__ int h[N_REL];
        int blk = b - HIST_BASE;
        for (int x = tid; x < N_REL; x += 256) h[x] = 0;
        __syncthreads();
        int e0 = blk * CHUNK;
        int e1 = e0 + CHUNK; if (e1 > N_EDGES) e1 = N_EDGES;
        for (int e = e0 + tid; e < e1; e += 256) {
            int r = rel[e]; r = r < 0 ? 0 : (r >= N_REL ? N_REL - 1 : r);
            atomicAdd(&h[r], 1);
        }
        __syncthreads();
        for (int x = tid; x < N_REL; x += 256)
            blockCountsT[x * NB_BLK + blk] = h[x];
    }
}

// Launch 2 — scan: one block. int4-reduce per-bin counts over chunks,
// Hillis-Steele scan of 16-padded totals, int4 prefix writes of per-chunk
// bases; persists offs/tots for the dummy writers.
__global__ __launch_bounds__(256) void scan_kernel(
    const int* __restrict__ blockCountsT,
    int* __restrict__ blockBaseT,
    int* __restrict__ offs, int* __restrict__ tots)
{
    __shared__ int s0[256];
    __shared__ int pval[256];
    int tid = threadIdx.x;
    int tot = 0;
    if (tid < N_REL) {
        const int4* cp = (const int4*)(blockCountsT + tid * NB_BLK);
        #pragma unroll 7
        for (int b = 0; b < NB_BLK / 4; b++) {
            int4 c = cp[b];
            tot += c.x + c.y + c.z + c.w;
        }
    }
    int p = (tid < N_REL) ? ((tot + 15) & ~15) : 0;
    pval[tid] = p;
    s0[tid] = p;
    __syncthreads();
    #pragma unroll
    for (int d = 1; d < 256; d <<= 1) {
        int v = s0[tid];
        if (tid >= d) v += s0[tid - d];
        __syncthreads();
        s0[tid] = v;
        __syncthreads();
    }
    int off = s0[tid] - pval[tid];     // exclusive scan of padded totals
    if (tid < N_REL) { offs[tid] = off; tots[tid] = tot; }
    if (tid == 255) offs[N_REL] = s0[255];   // padded grand total
    if (tid < N_REL) {
        const int4* cp = (const int4*)(blockCountsT + tid * NB_BLK);
        int4* bp = (int4*)(blockBaseT + tid * NB_BLK);
        int run = off;
        #pragma unroll 7
        for (int b = 0; b < NB_BLK / 4; b++) {
            int4 c = cp[b];
            int4 w;
            w.x = run;
            w.y = w.x + c.x;
            w.z = w.y + c.y;
            w.w = w.z + c.z;
            run = w.w + c.w;
            bp[b] = w;
        }
    }
}

// Launch 3 — gate+scatter FUSED (blocks [0,196)) + dummy writers ([196,204)).
// Each block runs the R5 gate on its own chunk (coalesced ttr/tre, 64-edge
// waves, 8 MFMAs + shfl-reduce + sigmoid) and immediately scatters each edge
// into its relation-sorted slot with the gate value packed inline
// ({s, t, a_bits, r}); no a_gate round-trip, one fewer streaming dispatch.
__global__ __launch_bounds__(256) void gatescatter_kernel(
    const float* __restrict__ node_feat,  // [N,32]
    const float* __restrict__ ttr,        // [E,32]
    const float* __restrict__ tre,        // [E,32]
    const float* __restrict__ Ab,         // [32]
    const float* __restrict__ Bw,         // [1,32]
    const float* __restrict__ Bb,         // [1]
    const int*  __restrict__ edge0,       // [E]
    const int*  __restrict__ edge1,       // [E]
    const int*  __restrict__ rel,         // [E]
    const unsigned short* __restrict__ aw_bf,   // [32][128] bf16
    const int* __restrict__ blockBaseT,
    const int* __restrict__ offs, const int* __restrict__ tots,
    int4* __restrict__ slot4)
{
    int b = blockIdx.x, tid = threadIdx.x;
    if (b >= NB_BLK) {
        // dummy writers: per-rel pad tails + global tail up to PE_MAX
        int db = b - NB_BLK;                 // 0..7
        const int4 dummy = make_int4(0, -1, 0, 0);
        for (int r = db; r < N_REL; r += N_DUMMY_BLOCKS) {
            int start = offs[r] + tots[r];
            int end   = offs[r] + ((tots[r] + 15) & ~15);
            for (int j = start + tid; j < end; j += 256)
                slot4[j] = dummy;
        }
        int padTotal = offs[N_REL];
        for (int j = padTotal + db * 256 + tid; j < PE_MAX; j += N_DUMMY_BLOCKS * 256)
            slot4[j] = dummy;
        return;
    }

    __shared__ int cur[N_REL];
    for (int x = tid; x < N_REL; x += 256)
        cur[x] = blockBaseT[x * NB_BLK + b];
    __syncthreads();

    int wave = tid >> 6;
    int lane = tid & 63;
    int m = lane & 15;          // edge row within group / out col
    int q = lane >> 4;          // k-chunk / row-group

    // gate weights: (m,q)-dependent only -> hoisted across the whole chunk
    short8 bA[4][2];
    #pragma unroll
    for (int hh = 0; hh < 2; hh++)
        #pragma unroll
        for (int c = 0; c < 4; c++)
            bA[c][hh] = *(const short8*)(aw_bf + (16 * hh + m) * 128 + 32 * c + 8 * q);
    float ab0 = Ab[m], ab1 = Ab[16 + m];
    float bw0 = Bw[m], bw1 = Bw[16 + m], Bb0 = Bb[0];

    int c0 = b * CHUNK;
    int cend = c0 + CHUNK; if (cend > N_EDGES) cend = N_EDGES;
    // chunk length is a multiple of 64 -> every wave-group fully valid
    for (int it = 0; it < CHUNK / 256; it++) {
        int ebase = c0 + it * 256 + wave * 64;
        if (ebase >= cend) continue;

        int e_lane = ebase + lane;
        int s_ld = edge0[e_lane]; s_ld = s_ld < 0 ? 0 : (s_ld >= N_NODES ? N_NODES - 1 : s_ld);
        int t_ld = edge1[e_lane]; t_ld = t_ld < 0 ? 0 : (t_ld >= N_NODES ? N_NODES - 1 : t_ld);
        int r_ld = rel[e_lane];   r_ld = r_ld < 0 ? 0 : (r_ld >= N_REL   ? N_REL   - 1 : r_ld);

        short8 fsrc[4], ftgt[4], fre_[4], ftr_[4];
        #pragma unroll
        for (int g = 0; g < 4; g++) {
            int s_m = __shfl(s_ld, g * 16 + m, 64);
            int t_m = __shfl(t_ld, g * 16 + m, 64);
            int e_m = ebase + g * 16 + m;
            const float* sp = node_feat + s_m * DIM + q * 8;
            float4 sv0 = *(const float4*)sp, sv1 = *(const float4*)(sp + 4);
            const float* tp = node_feat + t_m * DIM + q * 8;
            float4 tv0 = *(const float4*)tp, tv1 = *(const float4*)(tp + 4);
            const float* rp = tre + e_m * DIM + q * 8;      // coalesced stream
            float4 rv0 = *(const float4*)rp, rv1 = *(const float4*)(rp + 4);
            const float* qp = ttr + e_m * DIM + q * 8;      // coalesced stream
            float4 qv0 = *(const float4*)qp, qv1 = *(const float4*)(qp + 4);
            fsrc[g] = cvt8(sv0, sv1);
            ftgt[g] = cvt8(tv0, tv1);
            fre_[g] = cvt8(rv0, rv1);
            ftr_[g] = cvt8(qv0, qv1);
        }

        #pragma unroll
        for (int g = 0; g < 4; g++) {
            f32x4 h0 = {ab0, ab0, ab0, ab0};
            f32x4 h1 = {ab1, ab1, ab1, ab1};
            h0 = MFMA(fsrc[g], bA[0][0], h0);  h1 = MFMA(fsrc[g], bA[0][1], h1);
            h0 = MFMA(ftgt[g], bA[1][0], h0);  h1 = MFMA(ftgt[g], bA[1][1], h1);
            h0 = MFMA(fre_[g], bA[2][0], h0);  h1 = MFMA(fre_[g], bA[2][1], h1);
            h0 = MFMA(ftr_[g], bA[3][0], h0);  h1 = MFMA(ftr_[g], bA[3][1], h1);

            float av[4];
            #pragma unroll
            for (int v = 0; v < 4; v++) {
                float p = fmaxf(h0[v], 0.f) * bw0 + fmaxf(h1[v], 0.f) * bw1;
                p += __shfl_xor(p, 1, 16);
                p += __shfl_xor(p, 2, 16);
                p += __shfl_xor(p, 4, 16);
                p += __shfl_xor(p, 8, 16);
                av[v] = 1.f / (1.f + __expf(-(p + Bb0)));
            }
            // scatter group g: lanes (q, m<4) own edge j = g*16 + 4q + m;
            // av[m] is that edge's gate (row 4q+v computed in all m-lanes of
            // quad q). shfls executed by all lanes (static indexing, rule #20).
            int j = g * 16 + 4 * q + m;
            int s_j = __shfl(s_ld, j, 64);
            int t_j = __shfl(t_ld, j, 64);
            int r_j = __shfl(r_ld, j, 64);
            float a_j = (m == 0) ? av[0] : (m == 1) ? av[1]
                      : (m == 2) ? av[2] : av[3];
            if (m < 4) {
                int pos = atomicAdd(&cur[r_j], 1);
                slot4[pos] = make_int4(s_j, t_j, __float_as_int(a_j), r_j);
            }
        }
    }
}

// Launch 4 — edge: one wave = 64 slots (4 groups of 16; each 16-group is
// single-relation by padding). msg + per-edge self-loop via 4 MFMAs/group;
// out[t] += cur + a*msg. Dummy slots (tgt == -1) masked at the atomic.
__global__ __launch_bounds__(256) void edge_kernel(
    const float* __restrict__ node_feat,  // [N,32]
    const int4* __restrict__ slot4,       // [PE_MAX] {s, t(-1=dummy), a_bits, r}
    const unsigned short* __restrict__ relwT_bf, // [200][32][32] bf16 (T)
    const unsigned short* __restrict__ slwT_bf,  // [32][32] bf16 (T)
    float* __restrict__ out)              // [N,32] fp32 (pre-zeroed)
{
    int tid  = threadIdx.x;
    int wave = tid >> 6;
    int lane = tid & 63;
    int m = lane & 15;          // edge row (A-frag) / out col n (B,C/D frag)
    int q = lane >> 4;          // quad: k-range / row-group
    int wbase = blockIdx.x * 256 + wave * 64;   // 793*256 == PE_MAX exactly

    int4 v = slot4[wbase + lane];               // coalesced
    int s_ld = v.x, t_ld = v.y, a_ld = v.z, r_ld = v.w;

    short8 bS[2];
    bS[0] = *(const short8*)(slwT_bf + m * 32 + 8 * q);
    bS[1] = *(const short8*)(slwT_bf + (16 + m) * 32 + 8 * q);

    short8 fsrc[4], ftgt[4], bM[4][2];
    #pragma unroll
    for (int g = 0; g < 4; g++) {
        int r_g = __shfl(r_ld, g * 16, 64);     // uniform within group
        int s_m = __shfl(s_ld, g * 16 + m, 64);
        int t_m = __shfl(t_ld, g * 16 + m, 64);
        int t_mc = t_m < 0 ? 0 : t_m;
        const float* sp = node_feat + s_m * DIM + q * 8;
        float4 sv0 = *(const float4*)sp, sv1 = *(const float4*)(sp + 4);
        const float* tp = node_feat + t_mc * DIM + q * 8;
        float4 tv0 = *(const float4*)tp, tv1 = *(const float4*)(tp + 4);
        fsrc[g] = cvt8(sv0, sv1);
        ftgt[g] = cvt8(tv0, tv1);
        bM[g][0] = *(const short8*)(relwT_bf + r_g * 1024 + m * 32 + 8 * q);
        bM[g][1] = *(const short8*)(relwT_bf + r_g * 1024 + (16 + m) * 32 + 8 * q);
    }

    #pragma unroll
    for (int g = 0; g < 4; g++) {
        f32x4 m0 = {0.f, 0.f, 0.f, 0.f};
        f32x4 m1 = {0.f, 0.f, 0.f, 0.f};
        f32x4 c0 = {0.f, 0.f, 0.f, 0.f};
        f32x4 c1 = {0.f, 0.f, 0.f, 0.f};
        m0 = MFMA(fsrc[g], bM[g][0], m0);
        m1 = MFMA(fsrc[g], bM[g][1], m1);
        c0 = MFMA(ftgt[g], bS[0], c0);
        c1 = MFMA(ftgt[g], bS[1], c1);
        #pragma unroll
        for (int vv = 0; vv < 4; vv++) {
            int row = 4 * q + vv;
            int tv = __shfl(t_ld, g * 16 + row, 64);
            float a_row = __int_as_float(__shfl(a_ld, g * 16 + row, 64));
            if (tv >= 0) {
                atomicAdd(&out[tv * DIM + m],      c0[vv] + m0[vv] * a_row);
                atomicAdd(&out[tv * DIM + 16 + m], c1[vv] + m1[vv] * a_row);
            }
        }
    }
}

extern "C" void kernel_launch(void* const* d_in, const int* in_sizes, int n_in,
                              void* d_out, int out_size, void* d_ws, size_t ws_size,
                              hipStream_t stream) {
    const float* node_feat = (const float*)d_in[0];
    const float* ttr       = (const float*)d_in[1];
    const float* tre       = (const float*)d_in[2];
    const float* weight    = (const float*)d_in[3];
    const float* w_comp    = (const float*)d_in[4];
    const float* slw       = (const float*)d_in[5];
    const float* Aw        = (const float*)d_in[6];
    const float* Ab        = (const float*)d_in[7];
    const float* Bw        = (const float*)d_in[8];
    const float* Bb        = (const float*)d_in[9];
    const int*  total_edge = (const int*)d_in[10];
    const int*  rel        = (const int*)d_in[11];
    const int*  edge0 = total_edge;
    const int*  edge1 = total_edge + N_EDGES;

    char* ws = (char*)d_ws;
    unsigned short* relwT_bf = (unsigned short*)ws;
    unsigned short* aw_bf    = (unsigned short*)(ws + AWBF_OFF);
    unsigned short* slwT_bf  = (unsigned short*)(ws + SLWT_OFF);
    int*  blockCountsT = (int*)(ws + BCT_OFF);
    int*  blockBaseT   = (int*)(ws + BBT_OFF);
    int*  offs         = (int*)(ws + OFFS_OFF);
    int*  tots         = (int*)(ws + TOTS_OFF);
    int4* slot4        = (int4*)(ws + SLOT_OFF);
    float* out = (float*)d_out;

    prep_kernel<<<PREP_BLOCKS, 256, 0, stream>>>(
        weight, w_comp, Aw, slw, rel, relwT_bf, aw_bf, slwT_bf,
        blockCountsT, out);

    scan_kernel<<<1, 256, 0, stream>>>(blockCountsT, blockBaseT, offs, tots);

    gatescatter_kernel<<<NB_BLK + N_DUMMY_BLOCKS, 256, 0, stream>>>(
        node_feat, ttr, tre, Ab, Bw, Bb, edge0, edge1, rel,
        aw_bf, blockBaseT, offs, tots, slot4);

    edge_kernel<<<EDGE_BLOCKS, 256, 0, stream>>>(
        node_feat, slot4, relwT_bf, slwT_bf, out);
}